// Round 18
// baseline (337.772 us; speedup 1.0000x reference)
//
#include <hip/hip_runtime.h>
#include <hip/hip_bf16.h>

#define H_   128
#define B_   4
#define L_   2048
#define KN   24
#define M_   64
#define NROW (B_*L_*KN)   // 196608
#define LKR  (L_*KN)      // 49152

typedef float f32x4 __attribute__((ext_vector_type(4)));
typedef short s16x8 __attribute__((ext_vector_type(8)));
typedef unsigned u32x2 __attribute__((ext_vector_type(2)));

#define MFMA16(a,b,c) __builtin_amdgcn_mfma_f32_16x16x32_bf16((a),(b),(c),0,0,0)

static __device__ __forceinline__ unsigned short f2bfu(float x){
    union { __hip_bfloat16 h; unsigned short s; } u; u.h = __float2bfloat16(x); return u.s;
}
static __device__ __forceinline__ float bf2f(unsigned short s){
    union { unsigned short s; __hip_bfloat16 h; } u; u.s = s; return __bfloat162float(u.h);
}
static __device__ __forceinline__ unsigned packbf(float lo, float hi){
    return (unsigned)f2bfu(lo) | ((unsigned)f2bfu(hi) << 16);
}
// tanh-form gelu: |err| <= ~3e-3
static __device__ __forceinline__ float gelu_f(float x){
    const float x2 = x*x;
    const float u  = x * fmaf(x2, -0.10294265f, -2.3022083f);
    const float e  = __builtin_amdgcn_exp2f(u);
    return x * __builtin_amdgcn_rcpf(1.0f + e);
}
static __device__ __forceinline__ float wsum(float v){
#pragma unroll
    for (int m = 32; m; m >>= 1) v += __shfl_xor(v, m, 64);
    return v;
}
static __device__ __forceinline__ s16x8 cvt8(float4 p0, float4 p1){
    s16x8 v;
    v[0]=(short)f2bfu(p0.x); v[1]=(short)f2bfu(p0.y); v[2]=(short)f2bfu(p0.z); v[3]=(short)f2bfu(p0.w);
    v[4]=(short)f2bfu(p1.x); v[5]=(short)f2bfu(p1.y); v[6]=(short)f2bfu(p1.z); v[7]=(short)f2bfu(p1.w);
    return v;
}
// bf16 LDS, 16B-block XOR swizzle: element [r][c] at r*KW + ((c>>3 ^ (r&7))<<3) + (c&7)
template<int KW>
static __device__ __forceinline__ s16x8 afrag(const short* xs, int r, int blk){
    return *(const s16x8*)(xs + r*KW + ((blk ^ (r & 7)) << 3));
}
// paired 8B store: shorts c..c+3 (c % 4 == 0, within one 16B block)
template<int KW>
static __device__ __forceinline__ void bstore2(short* xs, int r, int c, unsigned lo, unsigned hi){
    u32x2 v; v[0] = lo; v[1] = hi;
    *(u32x2*)(xs + r*KW + ((((c >> 3) ^ (r & 7))) << 3) + (c & 7)) = v;
}

// ---- init: zero dh + pack weights fp32 [N][K] -> bf16 fragment-packed ----
struct PackArgs {
    const float* src[8];
    int K[8];
    int off[8];
};
#define PACK_TOTAL 294912
__global__ void k_init(PackArgs pa, short* __restrict__ dst, float* __restrict__ dh){
    const int gid = blockIdx.x*256 + threadIdx.x;
    if (gid < B_*M_*H_) dh[gid] = 0.0f;
    if (gid >= PACK_TOTAL) return;
    int w = 0;
#pragma unroll
    for (int i = 1; i < 8; ++i) if (gid >= pa.off[i]) w = i;
    const int e = gid - pa.off[w];
    const int K = pa.K[w];
    const int j = e & 7, lane = (e >> 3) & 63, tt = e >> 9;
    const int kt = K >> 5;
    const int tk = tt % kt, tn = tt / kt;
    const int row = tn*16 + (lane & 15);
    const int col = tk*32 + ((lane >> 4) << 3) + j;
    dst[gid] = (short)f2bfu(pa.src[w][(size_t)row*K + col]);
}

// ---- msg = W3(gelu(W2(gelu(W1([hY|hE|hV]))))), scatter-add into dh ----
// EXACT round-17 version.
__global__ __launch_bounds__(512, 4) void k_msg(
    const float* __restrict__ hY, const float* __restrict__ hE, const float* __restrict__ hV,
    const int* __restrict__ nn,
    const short* __restrict__ W1p, const float* __restrict__ B1,
    const short* __restrict__ W2p, const float* __restrict__ B2,
    const short* __restrict__ W3p, const float* __restrict__ B3,
    float* __restrict__ dh)
{
    __shared__ __align__(16) char pool[40960];
    short* xs  = (short*)pool;            // 24K [64][192]
    short* tb2 = (short*)pool;            // 16K alias over xs (xs dead after W1)
    short* tb1 = (short*)(pool + 24576);  // 16K [64][128]
    const int tid = threadIdx.x, lane = tid & 63, w = tid >> 6;
    const int cl = lane & 15, rq = lane >> 4;
    const int row0 = blockIdx.x * 64, b = row0 / LKR;
    const s16x8* W18 = (const s16x8*)W1p;

    f32x4 acc[4];
#pragma unroll
    for (int rf = 0; rf < 4; ++rf)
#pragma unroll
        for (int j = 0; j < 4; ++j) acc[rf][j] = B1[w*16 + rq*4 + j];

    // -------- half 0: concat cols 0..191 (hY | hE[0:64)) --------
    for (int c = tid; c < 64*24; c += 512){
        const int rr = c/24, kb = c - rr*24;
        const int k = kb*8;
        const int g = row0 + rr;
        const float* s = (k < 128) ? hY + (size_t)g*128 + k
                                   : hE + (size_t)g*128 + (k-128);
        float4 p0 = ((const float4*)s)[0], p1 = ((const float4*)s)[1];
        *(s16x8*)(xs + rr*192 + ((kb ^ (rr&7)) << 3)) = cvt8(p0, p1);
    }
    __syncthreads();
#pragma unroll
    for (int ks = 0; ks < 6; ++ks){
        const s16x8 wf = W18[(size_t)(w*12 + ks)*64 + lane];
        const int blk = ks*4 + rq;
#pragma unroll
        for (int rf = 0; rf < 4; ++rf){
            const s16x8 a = afrag<192>(xs, rf*16 + cl, blk);
            acc[rf] = MFMA16(wf, a, acc[rf]);
        }
    }
    __syncthreads();
    // -------- half 1: concat cols 192..383 (hE[64:128) | hV) --------
    for (int c = tid; c < 64*24; c += 512){
        const int rr = c/24, kb = c - rr*24;
        const int k = 192 + kb*8;
        const int g = row0 + rr;
        const float* s = (k < 256) ? hE + (size_t)g*128 + (k-128)
                                   : hV + (size_t)(g/KN)*128 + (k-256);
        float4 p0 = ((const float4*)s)[0], p1 = ((const float4*)s)[1];
        *(s16x8*)(xs + rr*192 + ((kb ^ (rr&7)) << 3)) = cvt8(p0, p1);
    }
    __syncthreads();
#pragma unroll
    for (int ks = 0; ks < 6; ++ks){
        const s16x8 wf = W18[(size_t)(w*12 + 6 + ks)*64 + lane];
        const int blk = ks*4 + rq;
#pragma unroll
        for (int rf = 0; rf < 4; ++rf){
            const s16x8 a = afrag<192>(xs, rf*16 + cl, blk);
            acc[rf] = MFMA16(wf, a, acc[rf]);
        }
    }
#pragma unroll
    for (int rf = 0; rf < 4; ++rf){
        const int r = rf*16 + cl, cb = w*16 + rq*4;
        bstore2<128>(tb1, r, cb, packbf(gelu_f(acc[rf][0]), gelu_f(acc[rf][1])),
                                 packbf(gelu_f(acc[rf][2]), gelu_f(acc[rf][3])));
    }
    __syncthreads();   // all W1 xs reads done -> tb2 alias safe; tb1 visible

    // W2 (128->128): swapped
#pragma unroll
    for (int rf = 0; rf < 4; ++rf)
#pragma unroll
        for (int j = 0; j < 4; ++j) acc[rf][j] = B2[w*16 + rq*4 + j];
    {
        const s16x8* W8 = (const s16x8*)W2p;
#pragma unroll
        for (int ks = 0; ks < 4; ++ks){
            const s16x8 wf = W8[(size_t)(w*4 + ks)*64 + lane];
            const int blk = ks*4 + rq;
#pragma unroll
            for (int rf = 0; rf < 4; ++rf){
                const s16x8 a = afrag<128>(tb1, rf*16 + cl, blk);
                acc[rf] = MFMA16(wf, a, acc[rf]);
            }
        }
    }
#pragma unroll
    for (int rf = 0; rf < 4; ++rf){
        const int r = rf*16 + cl, cb = w*16 + rq*4;
        bstore2<128>(tb2, r, cb, packbf(gelu_f(acc[rf][0]), gelu_f(acc[rf][1])),
                                 packbf(gelu_f(acc[rf][2]), gelu_f(acc[rf][3])));
    }
    __syncthreads();

    // W3 (128->128): natural (feat=cl -> coalesced atomics)
#pragma unroll
    for (int rf = 0; rf < 4; ++rf){
        const float bv = B3[w*16 + cl];
        acc[rf] = (f32x4){bv,bv,bv,bv};
    }
    {
        const s16x8* W8 = (const s16x8*)W3p;
#pragma unroll
        for (int ks = 0; ks < 4; ++ks){
            const s16x8 wf = W8[(size_t)(w*4 + ks)*64 + lane];
            const int blk = ks*4 + rq;
#pragma unroll
            for (int rf = 0; rf < 4; ++rf){
                const s16x8 a = afrag<128>(tb2, rf*16 + cl, blk);
                acc[rf] = MFMA16(a, wf, acc[rf]);
            }
        }
    }
#pragma unroll
    for (int rf = 0; rf < 4; ++rf){
        int mj[4];
#pragma unroll
        for (int j = 0; j < 4; ++j) mj[j] = nn[row0 + rf*16 + rq*4 + j];
        const int c = w*16 + cl;
#pragma unroll
        for (int j = 0; j < 4; ++j)
            __hip_atomic_fetch_add(dh + ((size_t)(b*M_ + mj[j]))*128 + c, acc[rf][j],
                                   __ATOMIC_RELAXED, __HIP_MEMORY_SCOPE_AGENT);
    }
}

// ---- h_Y = LN2(y1 + Wout(gelu(Win(y1)))), y1 = LN1(hY + dh[b,nn]/Ys) ----
// Round-17 body; LN1 now computed DIRECTLY from global (wave-per-row wsum,
// same pattern as k_he's LN3) -- tfh staging + 3 barriers removed.
__global__ __launch_bounds__(512, 4) void k_hy(
    const float* __restrict__ hY, const float* __restrict__ dh, const float* __restrict__ Ys,
    const int* __restrict__ nn,
    const short* __restrict__ Winp, const float* __restrict__ Bin,
    const short* __restrict__ Woutp, const float* __restrict__ Bout,
    const float* __restrict__ n1s, const float* __restrict__ n1b,
    const float* __restrict__ n2s, const float* __restrict__ n2b,
    float* __restrict__ outY)
{
    __shared__ __align__(16) char pool[32768];
    short* xb  = (short*)pool;             // 16K [64][128] y1 bf16
    short* ffc = (short*)(pool + 16384);   // 16K [64][128] per-pass ff chunk
    short* wob = (short*)(pool + 16384);   // 16K [64][128] bf16 Wout out (alias)
    const int tid = threadIdx.x, lane = tid & 63, w = tid >> 6;
    const int cl = lane & 15, rq = lane >> 4;
    const int row0 = blockIdx.x * 64, b = row0 / LKR;
    const s16x8* Wi8 = (const s16x8*)Winp;
    const s16x8* Wo8 = (const s16x8*)Woutp;

    // ---- gather + scale + LN1 directly from global -> xb ----
#pragma unroll
    for (int i = 0; i < 8; ++i){
        const int r = w*8 + i, g = row0 + r;
        const int m = nn[g];
        const float inv = 1.0f / Ys[b*M_ + m];
        const float* ar = hY + (size_t)g*128;
        const float* dr = dh + ((size_t)(b*M_ + m))*128;
        const float v0 = fmaf(dr[lane],      inv, ar[lane]);
        const float v1 = fmaf(dr[lane + 64], inv, ar[lane + 64]);
        const float mu = wsum(v0+v1) * (1.0f/128.0f);
        const float d0 = v0-mu, d1 = v1-mu;
        const float var = wsum(d0*d0 + d1*d1) * (1.0f/128.0f);
        const float rs = rsqrtf(var + 1e-5f);
        const float y0 = d0*rs*n1s[lane]    + n1b[lane];
        const float y1 = d1*rs*n1s[lane+64] + n1b[lane+64];
        const int c1 = lane + 64;
        xb[r*128 + ((((lane>>3) ^ (r&7))) << 3) + (lane&7)] = (short)f2bfu(y0);
        xb[r*128 + ((((c1>>3)   ^ (r&7))) << 3) + (c1&7)]   = (short)f2bfu(y1);
    }
    __syncthreads();   // xb visible to all waves before FFN a-frag reads

    // ---- FFN: 4 passes of 128 ff-cols; Wout accumulated ----
    f32x4 accW[4];
#pragma unroll
    for (int rf = 0; rf < 4; ++rf)
#pragma unroll
        for (int j = 0; j < 4; ++j) accW[rf][j] = Bout[w*16 + rq*4 + j];

    for (int p = 0; p < 4; ++p){
        f32x4 ai[4];
#pragma unroll
        for (int rf = 0; rf < 4; ++rf)
#pragma unroll
            for (int j = 0; j < 4; ++j) ai[rf][j] = Bin[p*128 + w*16 + rq*4 + j];
#pragma unroll
        for (int ks = 0; ks < 4; ++ks){
            const s16x8 wf = Wi8[(size_t)((p*8 + w)*4 + ks)*64 + lane];
            const int blk = ks*4 + rq;
#pragma unroll
            for (int rf = 0; rf < 4; ++rf){
                const s16x8 a = afrag<128>(xb, rf*16 + cl, blk);
                ai[rf] = MFMA16(wf, a, ai[rf]);
            }
        }
        __syncthreads();   // previous pass's Wout reads of ffc complete
#pragma unroll
        for (int rf = 0; rf < 4; ++rf){
            const int r = rf*16 + cl, cb = w*16 + rq*4;
            bstore2<128>(ffc, r, cb, packbf(gelu_f(ai[rf][0]), gelu_f(ai[rf][1])),
                                     packbf(gelu_f(ai[rf][2]), gelu_f(ai[rf][3])));
        }
        __syncthreads();
#pragma unroll
        for (int ks = 0; ks < 4; ++ks){
            const s16x8 wf = Wo8[(size_t)(w*16 + p*4 + ks)*64 + lane];
            const int blk = ks*4 + rq;
#pragma unroll
            for (int rf = 0; rf < 4; ++rf){
                const s16x8 a = afrag<128>(ffc, rf*16 + cl, blk);
                accW[rf] = MFMA16(wf, a, accW[rf]);
            }
        }
    }
    __syncthreads();   // all ffc reads done -> wob alias safe

    // ---- Wout result -> wob (bf16, swizzled) ----
#pragma unroll
    for (int rf = 0; rf < 4; ++rf){
        const int r = rf*16 + cl, cb = w*16 + rq*4;
        bstore2<128>(wob, r, cb, packbf(accW[rf][0], accW[rf][1]),
                                 packbf(accW[rf][2], accW[rf][3]));
    }
    __syncthreads();

    // ---- LN2 with residual from xb -> outY ----
#pragma unroll
    for (int i = 0; i < 8; ++i){
        const int r = w*8 + i, g = row0 + r;
        const int c1 = lane + 64;
        const int s0i = r*128 + ((((lane>>3) ^ (r&7))) << 3) + (lane&7);
        const int s1i = r*128 + ((((c1>>3)   ^ (r&7))) << 3) + (c1&7);
        const float v0 = bf2f((unsigned short)xb[s0i]) + bf2f((unsigned short)wob[s0i]);
        const float v1 = bf2f((unsigned short)xb[s1i]) + bf2f((unsigned short)wob[s1i]);
        const float mu = wsum(v0+v1) * (1.0f/128.0f);
        const float d0 = v0-mu, d1 = v1-mu;
        const float var = wsum(d0*d0 + d1*d1) * (1.0f/128.0f);
        const float rs = rsqrtf(var + 1e-5f);
        outY[(size_t)g*128 + lane]      = d0*rs*n2s[lane]    + n2b[lane];
        outY[(size_t)g*128 + lane + 64] = d1*rs*n2s[lane+64] + n2b[lane+64];
    }
}

// ---- h_E = LN3( hE + W13(gelu(W12(gelu(W11([h_Y|hE|hV]))))) ) ----
// EXACT round-17 version.
__global__ __launch_bounds__(512, 4) void k_he(
    const float* __restrict__ hYn, const float* __restrict__ hE, const float* __restrict__ hV,
    const short* __restrict__ W1p, const float* __restrict__ B1,
    const short* __restrict__ W2p, const float* __restrict__ B2,
    const short* __restrict__ W3p, const float* __restrict__ B3,
    const float* __restrict__ n3s, const float* __restrict__ n3b,
    float* __restrict__ outE)
{
    __shared__ __align__(16) char pool[40960];
    short* xs  = (short*)pool;            // 24K [64][192]
    short* tb2 = (short*)pool;            // 16K alias over xs
    short* tb1 = (short*)(pool + 24576);  // 16K
    const int tid = threadIdx.x, lane = tid & 63, w = tid >> 6;
    const int cl = lane & 15, rq = lane >> 4;
    const int row0 = blockIdx.x * 64;
    const s16x8* W18 = (const s16x8*)W1p;

    f32x4 acc[4];
#pragma unroll
    for (int rf = 0; rf < 4; ++rf)
#pragma unroll
        for (int j = 0; j < 4; ++j) acc[rf][j] = B1[w*16 + rq*4 + j];

    // half 0: concat cols 0..191 (h_Y | hE[0:64))
    for (int c = tid; c < 64*24; c += 512){
        const int rr = c/24, kb = c - rr*24;
        const int k = kb*8;
        const int g = row0 + rr;
        const float* s = (k < 128) ? hYn + (size_t)g*128 + k
                                   : hE  + (size_t)g*128 + (k-128);
        float4 p0 = ((const float4*)s)[0], p1 = ((const float4*)s)[1];
        *(s16x8*)(xs + rr*192 + ((kb ^ (rr&7)) << 3)) = cvt8(p0, p1);
    }
    __syncthreads();
#pragma unroll
    for (int ks = 0; ks < 6; ++ks){
        const s16x8 wf = W18[(size_t)(w*12 + ks)*64 + lane];
        const int blk = ks*4 + rq;
#pragma unroll
        for (int rf = 0; rf < 4; ++rf){
            const s16x8 a = afrag<192>(xs, rf*16 + cl, blk);
            acc[rf] = MFMA16(wf, a, acc[rf]);
        }
    }
    __syncthreads();
    // half 1: concat cols 192..383 (hE[64:128) | hV)
    for (int c = tid; c < 64*24; c += 512){
        const int rr = c/24, kb = c - rr*24;
        const int k = 192 + kb*8;
        const int g = row0 + rr;
        const float* s = (k < 256) ? hE + (size_t)g*128 + (k-128)
                                   : hV + (size_t)(g/KN)*128 + (k-256);
        float4 p0 = ((const float4*)s)[0], p1 = ((const float4*)s)[1];
        *(s16x8*)(xs + rr*192 + ((kb ^ (rr&7)) << 3)) = cvt8(p0, p1);
    }
    __syncthreads();
#pragma unroll
    for (int ks = 0; ks < 6; ++ks){
        const s16x8 wf = W18[(size_t)(w*12 + 6 + ks)*64 + lane];
        const int blk = ks*4 + rq;
#pragma unroll
        for (int rf = 0; rf < 4; ++rf){
            const s16x8 a = afrag<192>(xs, rf*16 + cl, blk);
            acc[rf] = MFMA16(wf, a, acc[rf]);
        }
    }
#pragma unroll
    for (int rf = 0; rf < 4; ++rf){
        const int r = rf*16 + cl, cb = w*16 + rq*4;
        bstore2<128>(tb1, r, cb, packbf(gelu_f(acc[rf][0]), gelu_f(acc[rf][1])),
                                 packbf(gelu_f(acc[rf][2]), gelu_f(acc[rf][3])));
    }
    __syncthreads();   // xs reads done -> tb2 alias safe

    // W12
#pragma unroll
    for (int rf = 0; rf < 4; ++rf)
#pragma unroll
        for (int j = 0; j < 4; ++j) acc[rf][j] = B2[w*16 + rq*4 + j];
    {
        const s16x8* W8 = (const s16x8*)W2p;
#pragma unroll
        for (int ks = 0; ks < 4; ++ks){
            const s16x8 wf = W8[(size_t)(w*4 + ks)*64 + lane];
            const int blk = ks*4 + rq;
#pragma unroll
            for (int rf = 0; rf < 4; ++rf){
                const s16x8 a = afrag<128>(tb1, rf*16 + cl, blk);
                acc[rf] = MFMA16(wf, a, acc[rf]);
            }
        }
    }
#pragma unroll
    for (int rf = 0; rf < 4; ++rf){
        const int r = rf*16 + cl, cb = w*16 + rq*4;
        bstore2<128>(tb2, r, cb, packbf(gelu_f(acc[rf][0]), gelu_f(acc[rf][1])),
                                 packbf(gelu_f(acc[rf][2]), gelu_f(acc[rf][3])));
    }
    __syncthreads();

    // W13
#pragma unroll
    for (int rf = 0; rf < 4; ++rf)
#pragma unroll
        for (int j = 0; j < 4; ++j) acc[rf][j] = B3[w*16 + rq*4 + j];
    {
        const s16x8* W8 = (const s16x8*)W3p;
#pragma unroll
        for (int ks = 0; ks < 4; ++ks){
            const s16x8 wf = W8[(size_t)(w*4 + ks)*64 + lane];
            const int blk = ks*4 + rq;
#pragma unroll
            for (int rf = 0; rf < 4; ++rf){
                const s16x8 a = afrag<128>(tb2, rf*16 + cl, blk);
                acc[rf] = MFMA16(wf, a, acc[rf]);
            }
        }
    }
#pragma unroll
    for (int rf = 0; rf < 4; ++rf){
        const int r = rf*16 + cl, cb = w*16 + rq*4;
        bstore2<128>(tb1, r, cb, packbf(acc[rf][0], acc[rf][1]),
                                 packbf(acc[rf][2], acc[rf][3]));
    }
    __syncthreads();

    // residual (fp32 hE) + LN3 -> outE
#pragma unroll
    for (int i = 0; i < 8; ++i){
        const int r = w*8 + i, g = row0 + r;
        const int c1 = lane + 64;
        const float m0 = bf2f((unsigned short)tb1[r*128 + ((((lane>>3) ^ (r&7))) << 3) + (lane&7)]);
        const float m1 = bf2f((unsigned short)tb1[r*128 + ((((c1>>3)   ^ (r&7))) << 3) + (c1&7)]);
        const float v0 = m0 + hE[(size_t)g*128 + lane];
        const float v1 = m1 + hE[(size_t)g*128 + lane + 64];
        const float mu = wsum(v0+v1) * (1.0f/128.0f);
        const float d0 = v0-mu, d1 = v1-mu;
        const float var = wsum(d0*d0 + d1*d1) * (1.0f/128.0f);
        const float rs = rsqrtf(var + 1e-5f);
        outE[(size_t)g*128 + lane]      = d0*rs*n3s[lane]    + n3b[lane];
        outE[(size_t)g*128 + lane + 64] = d1*rs*n3s[lane+64] + n3b[lane+64];
    }
}

extern "C" void kernel_launch(void* const* d_in, const int* in_sizes, int n_in,
                              void* d_out, int out_size, void* d_ws, size_t ws_size,
                              hipStream_t stream) {
    const int*   nn   = (const int*)  d_in[0];
    const float* Ys   = (const float*)d_in[1];
    const float* hY   = (const float*)d_in[2];
    const float* hE   = (const float*)d_in[3];
    const float* hV   = (const float*)d_in[4];
    const float* W1w  = (const float*)d_in[5];  const float* W1b  = (const float*)d_in[6];
    const float* W2w  = (const float*)d_in[7];  const float* W2b  = (const float*)d_in[8];
    const float* W3w  = (const float*)d_in[9];  const float* W3b  = (const float*)d_in[10];
    const float* W11w = (const float*)d_in[11]; const float* W11b = (const float*)d_in[12];
    const float* W12w = (const float*)d_in[13]; const float* W12b = (const float*)d_in[14];
    const float* W13w = (const float*)d_in[15]; const float* W13b = (const float*)d_in[16];
    const float* Winw = (const float*)d_in[17]; const float* Winb = (const float*)d_in[18];
    const float* Woutw= (const float*)d_in[19]; const float* Woutb= (const float*)d_in[20];
    const float* n1s  = (const float*)d_in[21]; const float* n1b  = (const float*)d_in[22];
    const float* n2s  = (const float*)d_in[23]; const float* n2b  = (const float*)d_in[24];
    const float* n3s  = (const float*)d_in[25]; const float* n3b  = (const float*)d_in[26];

    float* outY = (float*)d_out;
    float* outE = outY + (size_t)NROW * H_;

    float* dh = (float*)d_ws;                        // 128 KB
    short* wp = (short*)((char*)d_ws + 131072);      // packed bf16 weights (576 KB)

    const int oW1 = 0,       oW2 = 49152,   oW3 = 65536,   oW11 = 81920;
    const int oW12 = 131072, oW13 = 147456, oWin = 163840, oWout = 229376;

    PackArgs pa;
    pa.src[0]=W1w;  pa.K[0]=384; pa.off[0]=oW1;
    pa.src[1]=W2w;  pa.K[1]=128; pa.off[1]=oW2;
    pa.src[2]=W3w;  pa.K[2]=128; pa.off[2]=oW3;
    pa.src[3]=W11w; pa.K[3]=384; pa.off[3]=oW11;
    pa.src[4]=W12w; pa.K[4]=128; pa.off[4]=oW12;
    pa.src[5]=W13w; pa.K[5]=128; pa.off[5]=oW13;
    pa.src[6]=Winw; pa.K[6]=128; pa.off[6]=oWin;
    pa.src[7]=Woutw;pa.K[7]=512; pa.off[7]=oWout;

    const int nblk = NROW / 64;   // 3072

    k_init <<<(PACK_TOTAL + 255)/256, 256, 0, stream>>>(pa, wp, dh);
    k_msg  <<<nblk, 512, 0, stream>>>(hY, hE, hV, nn,
                                      wp + oW1, W1b, wp + oW2, W2b, wp + oW3, W3b, dh);
    k_hy   <<<nblk, 512, 0, stream>>>(hY, dh, Ys, nn, wp + oWin, Winb, wp + oWout, Woutb,
                                      n1s, n1b, n2s, n2b, outY);
    k_he   <<<nblk, 512, 0, stream>>>(outY, hE, hV,
                                      wp + oW11, W11b, wp + oW12, W12b, wp + oW13, W13b,
                                      n3s, n3b, outE);
}

// Round 19
// 327.429 us; speedup vs baseline: 1.0316x; 1.0316x over previous
//
#include <hip/hip_runtime.h>
#include <hip/hip_bf16.h>

#define H_   128
#define B_   4
#define L_   2048
#define KN   24
#define M_   64
#define NROW (B_*L_*KN)   // 196608
#define LKR  (L_*KN)      // 49152

typedef float f32x4 __attribute__((ext_vector_type(4)));
typedef short s16x8 __attribute__((ext_vector_type(8)));
typedef unsigned u32x2 __attribute__((ext_vector_type(2)));

#define MFMA16(a,b,c) __builtin_amdgcn_mfma_f32_16x16x32_bf16((a),(b),(c),0,0,0)

static __device__ __forceinline__ unsigned short f2bfu(float x){
    union { __hip_bfloat16 h; unsigned short s; } u; u.h = __float2bfloat16(x); return u.s;
}
static __device__ __forceinline__ float bf2f(unsigned short s){
    union { unsigned short s; __hip_bfloat16 h; } u; u.s = s; return __bfloat162float(u.h);
}
static __device__ __forceinline__ unsigned packbf(float lo, float hi){
    return (unsigned)f2bfu(lo) | ((unsigned)f2bfu(hi) << 16);
}
// tanh-form gelu: |err| <= ~3e-3
static __device__ __forceinline__ float gelu_f(float x){
    const float x2 = x*x;
    const float u  = x * fmaf(x2, -0.10294265f, -2.3022083f);
    const float e  = __builtin_amdgcn_exp2f(u);
    return x * __builtin_amdgcn_rcpf(1.0f + e);
}
static __device__ __forceinline__ float wsum(float v){
#pragma unroll
    for (int m = 32; m; m >>= 1) v += __shfl_xor(v, m, 64);
    return v;
}
static __device__ __forceinline__ s16x8 cvt8(float4 p0, float4 p1){
    s16x8 v;
    v[0]=(short)f2bfu(p0.x); v[1]=(short)f2bfu(p0.y); v[2]=(short)f2bfu(p0.z); v[3]=(short)f2bfu(p0.w);
    v[4]=(short)f2bfu(p1.x); v[5]=(short)f2bfu(p1.y); v[6]=(short)f2bfu(p1.z); v[7]=(short)f2bfu(p1.w);
    return v;
}
// bf16 LDS, 16B-block XOR swizzle: element [r][c] at r*KW + ((c>>3 ^ (r&7))<<3) + (c&7)
template<int KW>
static __device__ __forceinline__ s16x8 afrag(const short* xs, int r, int blk){
    return *(const s16x8*)(xs + r*KW + ((blk ^ (r & 7)) << 3));
}
// paired 8B store: shorts c..c+3 (c % 4 == 0, within one 16B block)
template<int KW>
static __device__ __forceinline__ void bstore2(short* xs, int r, int c, unsigned lo, unsigned hi){
    u32x2 v; v[0] = lo; v[1] = hi;
    *(u32x2*)(xs + r*KW + ((((c >> 3) ^ (r & 7))) << 3) + (c & 7)) = v;
}
// fp32 LDS, 16B-block XOR swizzle (width 128)
static __device__ __forceinline__ int fidx(int r, int c){
    return r*128 + ((((c >> 2) ^ (r & 7))) << 2) + (c & 3);
}

// ---- init: zero dh + pack weights fp32 [N][K] -> bf16 fragment-packed ----
struct PackArgs {
    const float* src[8];
    int K[8];
    int off[8];
};
#define PACK_TOTAL 294912
__global__ void k_init(PackArgs pa, short* __restrict__ dst, float* __restrict__ dh){
    const int gid = blockIdx.x*256 + threadIdx.x;
    if (gid < B_*M_*H_) dh[gid] = 0.0f;
    if (gid >= PACK_TOTAL) return;
    int w = 0;
#pragma unroll
    for (int i = 1; i < 8; ++i) if (gid >= pa.off[i]) w = i;
    const int e = gid - pa.off[w];
    const int K = pa.K[w];
    const int j = e & 7, lane = (e >> 3) & 63, tt = e >> 9;
    const int kt = K >> 5;
    const int tk = tt % kt, tn = tt / kt;
    const int row = tn*16 + (lane & 15);
    const int col = tk*32 + ((lane >> 4) << 3) + j;
    dst[gid] = (short)f2bfu(pa.src[w][(size_t)row*K + col]);
}

// ---- msg = W3(gelu(W2(gelu(W1([hY|hE|hV]))))), scatter-add into dh ----
__global__ __launch_bounds__(512, 4) void k_msg(
    const float* __restrict__ hY, const float* __restrict__ hE, const float* __restrict__ hV,
    const int* __restrict__ nn,
    const short* __restrict__ W1p, const float* __restrict__ B1,
    const short* __restrict__ W2p, const float* __restrict__ B2,
    const short* __restrict__ W3p, const float* __restrict__ B3,
    float* __restrict__ dh)
{
    __shared__ __align__(16) char pool[40960];
    short* xs  = (short*)pool;            // 24K [64][192]
    short* tb2 = (short*)pool;            // 16K alias over xs (xs dead after W1)
    short* tb1 = (short*)(pool + 24576);  // 16K [64][128]
    const int tid = threadIdx.x, lane = tid & 63, w = tid >> 6;
    const int cl = lane & 15, rq = lane >> 4;
    const int row0 = blockIdx.x * 64, b = row0 / LKR;
    const s16x8* W18 = (const s16x8*)W1p;

    f32x4 acc[4];
#pragma unroll
    for (int rf = 0; rf < 4; ++rf)
#pragma unroll
        for (int j = 0; j < 4; ++j) acc[rf][j] = B1[w*16 + rq*4 + j];

    // -------- half 0: concat cols 0..191 (hY | hE[0:64)) --------
    for (int c = tid; c < 64*24; c += 512){
        const int rr = c/24, kb = c - rr*24;
        const int k = kb*8;
        const int g = row0 + rr;
        const float* s = (k < 128) ? hY + (size_t)g*128 + k
                                   : hE + (size_t)g*128 + (k-128);
        float4 p0 = ((const float4*)s)[0], p1 = ((const float4*)s)[1];
        *(s16x8*)(xs + rr*192 + ((kb ^ (rr&7)) << 3)) = cvt8(p0, p1);
    }
    __syncthreads();
#pragma unroll
    for (int ks = 0; ks < 6; ++ks){
        const s16x8 wf = W18[(size_t)(w*12 + ks)*64 + lane];
        const int blk = ks*4 + rq;
#pragma unroll
        for (int rf = 0; rf < 4; ++rf){
            const s16x8 a = afrag<192>(xs, rf*16 + cl, blk);
            acc[rf] = MFMA16(wf, a, acc[rf]);
        }
    }
    __syncthreads();
    // -------- half 1: concat cols 192..383 (hE[64:128) | hV) --------
    for (int c = tid; c < 64*24; c += 512){
        const int rr = c/24, kb = c - rr*24;
        const int k = 192 + kb*8;
        const int g = row0 + rr;
        const float* s = (k < 256) ? hE + (size_t)g*128 + (k-128)
                                   : hV + (size_t)(g/KN)*128 + (k-256);
        float4 p0 = ((const float4*)s)[0], p1 = ((const float4*)s)[1];
        *(s16x8*)(xs + rr*192 + ((kb ^ (rr&7)) << 3)) = cvt8(p0, p1);
    }
    __syncthreads();
#pragma unroll
    for (int ks = 0; ks < 6; ++ks){
        const s16x8 wf = W18[(size_t)(w*12 + 6 + ks)*64 + lane];
        const int blk = ks*4 + rq;
#pragma unroll
        for (int rf = 0; rf < 4; ++rf){
            const s16x8 a = afrag<192>(xs, rf*16 + cl, blk);
            acc[rf] = MFMA16(wf, a, acc[rf]);
        }
    }
#pragma unroll
    for (int rf = 0; rf < 4; ++rf){
        const int r = rf*16 + cl, cb = w*16 + rq*4;
        bstore2<128>(tb1, r, cb, packbf(gelu_f(acc[rf][0]), gelu_f(acc[rf][1])),
                                 packbf(gelu_f(acc[rf][2]), gelu_f(acc[rf][3])));
    }
    __syncthreads();   // all W1 xs reads done -> tb2 alias safe; tb1 visible

    // W2 (128->128): swapped
#pragma unroll
    for (int rf = 0; rf < 4; ++rf)
#pragma unroll
        for (int j = 0; j < 4; ++j) acc[rf][j] = B2[w*16 + rq*4 + j];
    {
        const s16x8* W8 = (const s16x8*)W2p;
#pragma unroll
        for (int ks = 0; ks < 4; ++ks){
            const s16x8 wf = W8[(size_t)(w*4 + ks)*64 + lane];
            const int blk = ks*4 + rq;
#pragma unroll
            for (int rf = 0; rf < 4; ++rf){
                const s16x8 a = afrag<128>(tb1, rf*16 + cl, blk);
                acc[rf] = MFMA16(wf, a, acc[rf]);
            }
        }
    }
#pragma unroll
    for (int rf = 0; rf < 4; ++rf){
        const int r = rf*16 + cl, cb = w*16 + rq*4;
        bstore2<128>(tb2, r, cb, packbf(gelu_f(acc[rf][0]), gelu_f(acc[rf][1])),
                                 packbf(gelu_f(acc[rf][2]), gelu_f(acc[rf][3])));
    }
    __syncthreads();

    // W3 (128->128): natural (feat=cl -> coalesced atomics)
#pragma unroll
    for (int rf = 0; rf < 4; ++rf){
        const float bv = B3[w*16 + cl];
        acc[rf] = (f32x4){bv,bv,bv,bv};
    }
    {
        const s16x8* W8 = (const s16x8*)W3p;
#pragma unroll
        for (int ks = 0; ks < 4; ++ks){
            const s16x8 wf = W8[(size_t)(w*4 + ks)*64 + lane];
            const int blk = ks*4 + rq;
#pragma unroll
            for (int rf = 0; rf < 4; ++rf){
                const s16x8 a = afrag<128>(tb2, rf*16 + cl, blk);
                acc[rf] = MFMA16(a, wf, acc[rf]);
            }
        }
    }
#pragma unroll
    for (int rf = 0; rf < 4; ++rf){
        int mj[4];
#pragma unroll
        for (int j = 0; j < 4; ++j) mj[j] = nn[row0 + rf*16 + rq*4 + j];
        const int c = w*16 + cl;
#pragma unroll
        for (int j = 0; j < 4; ++j)
            __hip_atomic_fetch_add(dh + ((size_t)(b*M_ + mj[j]))*128 + c, acc[rf][j],
                                   __ATOMIC_RELAXED, __HIP_MEMORY_SCOPE_AGENT);
    }
}

// ---- h_Y = LN2(y1 + Wout(gelu(Win(y1)))), y1 = LN1(hY + dh[b,nn]/Ys) ----
__global__ __launch_bounds__(512, 4) void k_hy(
    const float* __restrict__ hY, const float* __restrict__ dh, const float* __restrict__ Ys,
    const int* __restrict__ nn,
    const short* __restrict__ Winp, const float* __restrict__ Bin,
    const short* __restrict__ Woutp, const float* __restrict__ Bout,
    const float* __restrict__ n1s, const float* __restrict__ n1b,
    const float* __restrict__ n2s, const float* __restrict__ n2b,
    float* __restrict__ outY)
{
    __shared__ __align__(16) char pool[32768];
    short* xb  = (short*)pool;             // 16K [64][128] y1 bf16
    float* tfh = (float*)(pool + 16384);   // 16K [32][128] fp32 stage (per half)
    short* ffc = (short*)(pool + 16384);   // 16K [64][128] per-pass ff chunk (alias)
    short* wob = (short*)(pool + 16384);   // 16K [64][128] bf16 Wout out (alias)
    const int tid = threadIdx.x, lane = tid & 63, w = tid >> 6;
    const int cl = lane & 15, rq = lane >> 4;
    const int row0 = blockIdx.x * 64, b = row0 / LKR;
    const s16x8* Wi8 = (const s16x8*)Winp;
    const s16x8* Wo8 = (const s16x8*)Woutp;

    // ---- prologue: two 32-row halves; stage fp32 -> tfh, wsum LN1 -> xb ----
#pragma unroll
    for (int ph = 0; ph < 2; ++ph){
        {   // stage rows [ph*32, ph*32+32): 512 items, one per thread
            const int r2 = tid >> 4;               // row within half
            const int k  = (tid & 15) << 3;
            const int g  = row0 + ph*32 + r2;
            const int m  = nn[g];
            const float inv = 1.0f / Ys[b*M_ + m];
            const float* a = hY + (size_t)g*128 + k;
            const float* d = dh + ((size_t)(b*M_ + m))*128 + k;
            float4 a0 = ((const float4*)a)[0], a1 = ((const float4*)a)[1];
            float4 d0 = ((const float4*)d)[0], d1 = ((const float4*)d)[1];
            float4 r0 = {fmaf(d0.x,inv,a0.x), fmaf(d0.y,inv,a0.y), fmaf(d0.z,inv,a0.z), fmaf(d0.w,inv,a0.w)};
            float4 r1 = {fmaf(d1.x,inv,a1.x), fmaf(d1.y,inv,a1.y), fmaf(d1.z,inv,a1.z), fmaf(d1.w,inv,a1.w)};
            const int s = r2 & 7, kb = k >> 2;
            *(float4*)&tfh[r2*128 + ((kb ^ s) << 2)]     = r0;
            *(float4*)&tfh[r2*128 + (((kb+1) ^ s) << 2)] = r1;
        }
        __syncthreads();
        // LN1: wave w owns rows ph*32 + w*4 + i  (r&7 == r2&7 since ph*32 % 8 == 0)
#pragma unroll
        for (int i = 0; i < 4; ++i){
            const int r2 = w*4 + i;
            const int r  = ph*32 + r2;
            const float v0 = tfh[fidx(r2, lane)], v1 = tfh[fidx(r2, lane+64)];
            const float mu = wsum(v0+v1) * (1.0f/128.0f);
            const float d0 = v0-mu, d1 = v1-mu;
            const float var = wsum(d0*d0 + d1*d1) * (1.0f/128.0f);
            const float rs = rsqrtf(var + 1e-5f);
            const float y0 = d0*rs*n1s[lane]    + n1b[lane];
            const float y1 = d1*rs*n1s[lane+64] + n1b[lane+64];
            const int c1 = lane + 64;
            xb[r*128 + ((((lane>>3) ^ (r&7))) << 3) + (lane&7)] = (short)f2bfu(y0);
            xb[r*128 + ((((c1>>3)   ^ (r&7))) << 3) + (c1&7)]   = (short)f2bfu(y1);
        }
        __syncthreads();   // tfh reads done before next half's stores / ffc writes
    }

    // ---- FFN: 4 passes of 128 ff-cols; Wout accumulated ----
    f32x4 accW[4];
#pragma unroll
    for (int rf = 0; rf < 4; ++rf)
#pragma unroll
        for (int j = 0; j < 4; ++j) accW[rf][j] = Bout[w*16 + rq*4 + j];

    for (int p = 0; p < 4; ++p){
        f32x4 ai[4];
#pragma unroll
        for (int rf = 0; rf < 4; ++rf)
#pragma unroll
            for (int j = 0; j < 4; ++j) ai[rf][j] = Bin[p*128 + w*16 + rq*4 + j];
#pragma unroll
        for (int ks = 0; ks < 4; ++ks){
            const s16x8 wf = Wi8[(size_t)((p*8 + w)*4 + ks)*64 + lane];
            const int blk = ks*4 + rq;
#pragma unroll
            for (int rf = 0; rf < 4; ++rf){
                const s16x8 a = afrag<128>(xb, rf*16 + cl, blk);
                ai[rf] = MFMA16(wf, a, ai[rf]);
            }
        }
        __syncthreads();   // previous pass's Wout reads of ffc complete
#pragma unroll
        for (int rf = 0; rf < 4; ++rf){
            const int r = rf*16 + cl, cb = w*16 + rq*4;
            bstore2<128>(ffc, r, cb, packbf(gelu_f(ai[rf][0]), gelu_f(ai[rf][1])),
                                     packbf(gelu_f(ai[rf][2]), gelu_f(ai[rf][3])));
        }
        __syncthreads();
#pragma unroll
        for (int ks = 0; ks < 4; ++ks){
            const s16x8 wf = Wo8[(size_t)(w*16 + p*4 + ks)*64 + lane];
            const int blk = ks*4 + rq;
#pragma unroll
            for (int rf = 0; rf < 4; ++rf){
                const s16x8 a = afrag<128>(ffc, rf*16 + cl, blk);
                accW[rf] = MFMA16(wf, a, accW[rf]);
            }
        }
    }
    __syncthreads();   // all ffc reads done -> wob alias safe

    // ---- Wout result -> wob (bf16, swizzled) ----
#pragma unroll
    for (int rf = 0; rf < 4; ++rf){
        const int r = rf*16 + cl, cb = w*16 + rq*4;
        bstore2<128>(wob, r, cb, packbf(accW[rf][0], accW[rf][1]),
                                 packbf(accW[rf][2], accW[rf][3]));
    }
    __syncthreads();

    // ---- LN2 with residual from xb -> outY ----
#pragma unroll
    for (int i = 0; i < 8; ++i){
        const int r = w*8 + i, g = row0 + r;
        const int c1 = lane + 64;
        const int s0i = r*128 + ((((lane>>3) ^ (r&7))) << 3) + (lane&7);
        const int s1i = r*128 + ((((c1>>3)   ^ (r&7))) << 3) + (c1&7);
        const float v0 = bf2f((unsigned short)xb[s0i]) + bf2f((unsigned short)wob[s0i]);
        const float v1 = bf2f((unsigned short)xb[s1i]) + bf2f((unsigned short)wob[s1i]);
        const float mu = wsum(v0+v1) * (1.0f/128.0f);
        const float d0 = v0-mu, d1 = v1-mu;
        const float var = wsum(d0*d0 + d1*d1) * (1.0f/128.0f);
        const float rs = rsqrtf(var + 1e-5f);
        outY[(size_t)g*128 + lane]      = d0*rs*n2s[lane]    + n2b[lane];
        outY[(size_t)g*128 + lane + 64] = d1*rs*n2s[lane+64] + n2b[lane+64];
    }
}

// ---- h_E = LN3( hE + W13(gelu(W12(gelu(W11([h_Y|hE|hV]))))) ) ----
__global__ __launch_bounds__(512, 4) void k_he(
    const float* __restrict__ hYn, const float* __restrict__ hE, const float* __restrict__ hV,
    const short* __restrict__ W1p, const float* __restrict__ B1,
    const short* __restrict__ W2p, const float* __restrict__ B2,
    const short* __restrict__ W3p, const float* __restrict__ B3,
    const float* __restrict__ n3s, const float* __restrict__ n3b,
    float* __restrict__ outE)
{
    __shared__ __align__(16) char pool[40960];
    short* xs  = (short*)pool;            // 24K [64][192]
    short* tb2 = (short*)pool;            // 16K alias over xs
    short* tb1 = (short*)(pool + 24576);  // 16K
    const int tid = threadIdx.x, lane = tid & 63, w = tid >> 6;
    const int cl = lane & 15, rq = lane >> 4;
    const int row0 = blockIdx.x * 64;
    const s16x8* W18 = (const s16x8*)W1p;

    f32x4 acc[4];
#pragma unroll
    for (int rf = 0; rf < 4; ++rf)
#pragma unroll
        for (int j = 0; j < 4; ++j) acc[rf][j] = B1[w*16 + rq*4 + j];

    // half 0: concat cols 0..191 (h_Y | hE[0:64))
    for (int c = tid; c < 64*24; c += 512){
        const int rr = c/24, kb = c - rr*24;
        const int k = kb*8;
        const int g = row0 + rr;
        const float* s = (k < 128) ? hYn + (size_t)g*128 + k
                                   : hE  + (size_t)g*128 + (k-128);
        float4 p0 = ((const float4*)s)[0], p1 = ((const float4*)s)[1];
        *(s16x8*)(xs + rr*192 + ((kb ^ (rr&7)) << 3)) = cvt8(p0, p1);
    }
    __syncthreads();
#pragma unroll
    for (int ks = 0; ks < 6; ++ks){
        const s16x8 wf = W18[(size_t)(w*12 + ks)*64 + lane];
        const int blk = ks*4 + rq;
#pragma unroll
        for (int rf = 0; rf < 4; ++rf){
            const s16x8 a = afrag<192>(xs, rf*16 + cl, blk);
            acc[rf] = MFMA16(wf, a, acc[rf]);
        }
    }
    __syncthreads();
    // half 1: concat cols 192..383 (hE[64:128) | hV)
    for (int c = tid; c < 64*24; c += 512){
        const int rr = c/24, kb = c - rr*24;
        const int k = 192 + kb*8;
        const int g = row0 + rr;
        const float* s = (k < 256) ? hE + (size_t)g*128 + (k-128)
                                   : hV + (size_t)(g/KN)*128 + (k-256);
        float4 p0 = ((const float4*)s)[0], p1 = ((const float4*)s)[1];
        *(s16x8*)(xs + rr*192 + ((kb ^ (rr&7)) << 3)) = cvt8(p0, p1);
    }
    __syncthreads();
#pragma unroll
    for (int ks = 0; ks < 6; ++ks){
        const s16x8 wf = W18[(size_t)(w*12 + 6 + ks)*64 + lane];
        const int blk = ks*4 + rq;
#pragma unroll
        for (int rf = 0; rf < 4; ++rf){
            const s16x8 a = afrag<192>(xs, rf*16 + cl, blk);
            acc[rf] = MFMA16(wf, a, acc[rf]);
        }
    }
#pragma unroll
    for (int rf = 0; rf < 4; ++rf){
        const int r = rf*16 + cl, cb = w*16 + rq*4;
        bstore2<128>(tb1, r, cb, packbf(gelu_f(acc[rf][0]), gelu_f(acc[rf][1])),
                                 packbf(gelu_f(acc[rf][2]), gelu_f(acc[rf][3])));
    }
    __syncthreads();   // xs reads done -> tb2 alias safe

    // W12
#pragma unroll
    for (int rf = 0; rf < 4; ++rf)
#pragma unroll
        for (int j = 0; j < 4; ++j) acc[rf][j] = B2[w*16 + rq*4 + j];
    {
        const s16x8* W8 = (const s16x8*)W2p;
#pragma unroll
        for (int ks = 0; ks < 4; ++ks){
            const s16x8 wf = W8[(size_t)(w*4 + ks)*64 + lane];
            const int blk = ks*4 + rq;
#pragma unroll
            for (int rf = 0; rf < 4; ++rf){
                const s16x8 a = afrag<128>(tb1, rf*16 + cl, blk);
                acc[rf] = MFMA16(wf, a, acc[rf]);
            }
        }
    }
#pragma unroll
    for (int rf = 0; rf < 4; ++rf){
        const int r = rf*16 + cl, cb = w*16 + rq*4;
        bstore2<128>(tb2, r, cb, packbf(gelu_f(acc[rf][0]), gelu_f(acc[rf][1])),
                                 packbf(gelu_f(acc[rf][2]), gelu_f(acc[rf][3])));
    }
    __syncthreads();

    // W13
#pragma unroll
    for (int rf = 0; rf < 4; ++rf)
#pragma unroll
        for (int j = 0; j < 4; ++j) acc[rf][j] = B3[w*16 + rq*4 + j];
    {
        const s16x8* W8 = (const s16x8*)W3p;
#pragma unroll
        for (int ks = 0; ks < 4; ++ks){
            const s16x8 wf = W8[(size_t)(w*4 + ks)*64 + lane];
            const int blk = ks*4 + rq;
#pragma unroll
            for (int rf = 0; rf < 4; ++rf){
                const s16x8 a = afrag<128>(tb2, rf*16 + cl, blk);
                acc[rf] = MFMA16(wf, a, acc[rf]);
            }
        }
    }
#pragma unroll
    for (int rf = 0; rf < 4; ++rf){
        const int r = rf*16 + cl, cb = w*16 + rq*4;
        bstore2<128>(tb1, r, cb, packbf(acc[rf][0], acc[rf][1]),
                                 packbf(acc[rf][2], acc[rf][3]));
    }
    __syncthreads();

    // residual (fp32 hE) + LN3 -> outE
#pragma unroll
    for (int i = 0; i < 8; ++i){
        const int r = w*8 + i, g = row0 + r;
        const int c1 = lane + 64;
        const float m0 = bf2f((unsigned short)tb1[r*128 + ((((lane>>3) ^ (r&7))) << 3) + (lane&7)]);
        const float m1 = bf2f((unsigned short)tb1[r*128 + ((((c1>>3)   ^ (r&7))) << 3) + (c1&7)]);
        const float v0 = m0 + hE[(size_t)g*128 + lane];
        const float v1 = m1 + hE[(size_t)g*128 + lane + 64];
        const float mu = wsum(v0+v1) * (1.0f/128.0f);
        const float d0 = v0-mu, d1 = v1-mu;
        const float var = wsum(d0*d0 + d1*d1) * (1.0f/128.0f);
        const float rs = rsqrtf(var + 1e-5f);
        outE[(size_t)g*128 + lane]      = d0*rs*n3s[lane]    + n3b[lane];
        outE[(size_t)g*128 + lane + 64] = d1*rs*n3s[lane+64] + n3b[lane+64];
    }
}

extern "C" void kernel_launch(void* const* d_in, const int* in_sizes, int n_in,
                              void* d_out, int out_size, void* d_ws, size_t ws_size,
                              hipStream_t stream) {
    const int*   nn   = (const int*)  d_in[0];
    const float* Ys   = (const float*)d_in[1];
    const float* hY   = (const float*)d_in[2];
    const float* hE   = (const float*)d_in[3];
    const float* hV   = (const float*)d_in[4];
    const float* W1w  = (const float*)d_in[5];  const float* W1b  = (const float*)d_in[6];
    const float* W2w  = (const float*)d_in[7];  const float* W2b  = (const float*)d_in[8];
    const float* W3w  = (const float*)d_in[9];  const float* W3b  = (const float*)d_in[10];
    const float* W11w = (const float*)d_in[11]; const float* W11b = (const float*)d_in[12];
    const float* W12w = (const float*)d_in[13]; const float* W12b = (const float*)d_in[14];
    const float* W13w = (const float*)d_in[15]; const float* W13b = (const float*)d_in[16];
    const float* Winw = (const float*)d_in[17]; const float* Winb = (const float*)d_in[18];
    const float* Woutw= (const float*)d_in[19]; const float* Woutb= (const float*)d_in[20];
    const float* n1s  = (const float*)d_in[21]; const float* n1b  = (const float*)d_in[22];
    const float* n2s  = (const float*)d_in[23]; const float* n2b  = (const float*)d_in[24];
    const float* n3s  = (const float*)d_in[25]; const float* n3b  = (const float*)d_in[26];

    float* outY = (float*)d_out;
    float* outE = outY + (size_t)NROW * H_;

    float* dh = (float*)d_ws;                        // 128 KB
    short* wp = (short*)((char*)d_ws + 131072);      // packed bf16 weights (576 KB)

    const int oW1 = 0,       oW2 = 49152,   oW3 = 65536,   oW11 = 81920;
    const int oW12 = 131072, oW13 = 147456, oWin = 163840, oWout = 229376;

    PackArgs pa;
    pa.src[0]=W1w;  pa.K[0]=384; pa.off[0]=oW1;
    pa.src[1]=W2w;  pa.K[1]=128; pa.off[1]=oW2;
    pa.src[2]=W3w;  pa.K[2]=128; pa.off[2]=oW3;
    pa.src[3]=W11w; pa.K[3]=384; pa.off[3]=oW11;
    pa.src[4]=W12w; pa.K[4]=128; pa.off[4]=oW12;
    pa.src[5]=W13w; pa.K[5]=128; pa.off[5]=oW13;
    pa.src[6]=Winw; pa.K[6]=128; pa.off[6]=oWin;
    pa.src[7]=Woutw;pa.K[7]=512; pa.off[7]=oWout;

    const int nblk = NROW / 64;   // 3072

    k_init <<<(PACK_TOTAL + 255)/256, 256, 0, stream>>>(pa, wp, dh);
    k_msg  <<<nblk, 512, 0, stream>>>(hY, hE, hV, nn,
                                      wp + oW1, W1b, wp + oW2, W2b, wp + oW3, W3b, dh);
    k_hy   <<<nblk, 512, 0, stream>>>(hY, dh, Ys, nn, wp + oWin, Winb, wp + oWout, Woutb,
                                      n1s, n1b, n2s, n2b, outY);
    k_he   <<<nblk, 512, 0, stream>>>(outY, hE, hV,
                                      wp + oW11, W11b, wp + oW12, W12b, wp + oW13, W13b,
                                      n3s, n3b, outE);
}